// Round 12
// baseline (276.997 us; speedup 1.0000x reference)
//
#include <hip/hip_runtime.h>
#include <stdint.h>

#define NN 50000
#define NE 800000
#define NBIN 196   // dst buckets of 256 nodes (dst >> 8)
#define ABLK 196   // blocks in hist/bin passes
#define EPB 4082   // edges per block: 196*4082 >= NE
#define BCAP 6144  // per-bucket LDS capacity (avg 4096)
#define NRT 3125   // NN/16 row tiles
#define GRID_LIN 1024

typedef __attribute__((ext_vector_type(8))) short short8;
typedef __attribute__((ext_vector_type(4))) float floatx4;

__device__ __forceinline__ uint16_t f2bf(float f){
  union { float f; uint32_t u; } c; c.f = f;
  uint32_t u = c.u + 0x7FFFu + ((c.u >> 16) & 1u);
  return (uint16_t)(u >> 16);
}
__device__ __forceinline__ float bflo(uint32_t v){
  union { uint32_t u; float f; } c; c.u = v << 16; return c.f;
}
__device__ __forceinline__ float bfhi(uint32_t v){
  union { uint32_t u; float f; } c; c.u = v & 0xFFFF0000u; return c.f;
}

// ---------------- prep: bucket histogram (counts kept) + weight packs ----------------
#define B_HIST ABLK
#define B_PIN 64
#define B_P0  128
#define B_P1  128
#define B_P2  64

__device__ __forceinline__ void pack_one(int idx, const float* __restrict__ wl,
                                         const float* __restrict__ wr,
                                         uint16_t* __restrict__ bp,
                                         int ncolL, int ncolR, int NT){
  int j = idx & 7, lane = (idx >> 3) & 63, rest = idx >> 9;
  int nt = rest % NT, kt = rest / NT;
  int k = kt * 32 + ((lane >> 4) << 3) + j;
  int n = nt * 16 + (lane & 15);
  float v = (n < ncolL) ? wl[k * ncolL + n] : wr[k * ncolR + (n - ncolL)];
  bp[idx] = f2bf(v);
}

__global__ __launch_bounds__(256) void k_prep(const int* __restrict__ ei, int* __restrict__ histC,
                                              const float* __restrict__ w_in,
                                              const float* __restrict__ w_l0, const float* __restrict__ w_r0,
                                              const float* __restrict__ w_l1, const float* __restrict__ w_r1,
                                              const float* __restrict__ w_l2, const float* __restrict__ w_r2,
                                              uint16_t* __restrict__ bpIn, uint16_t* __restrict__ bp0,
                                              uint16_t* __restrict__ bp1, uint16_t* __restrict__ bp2){
  __shared__ int hsh[NBIN];
  int b = blockIdx.x;
  if (b < B_HIST){
    for (int i = threadIdx.x; i < NBIN; i += 256) hsh[i] = 0;
    __syncthreads();
    int base = b * EPB;
    for (int k = threadIdx.x; k < EPB; k += 256){
      int e = base + k;
      if (e < NE) atomicAdd(&hsh[ei[NE + e] >> 8], 1);
    }
    __syncthreads();
    for (int i = threadIdx.x; i < NBIN; i += 256) histC[b * NBIN + i] = hsh[i];
    return;
  }
  b -= B_HIST;
  if (b < B_PIN){ pack_one(b * 256 + threadIdx.x, w_in, w_in, bpIn, 128, 0, 8); return; }
  b -= B_PIN;
  if (b < B_P0){ pack_one(b * 256 + threadIdx.x, w_l0, w_r0, bp0, 128, 128, 16); return; }
  b -= B_P0;
  if (b < B_P1){ pack_one(b * 256 + threadIdx.x, w_l1, w_r1, bp1, 128, 128, 16); return; }
  b -= B_P1;
  pack_one(b * 256 + threadIdx.x, w_l2, w_r2, bp2, 64, 64, 8);
}

// ---------------- scan S1: one block per bin; within-column exclusive prefixes -> histE ----------------
__global__ __launch_bounds__(256) void k_scanS1(const int* __restrict__ histC, int* __restrict__ histE,
                                                int* __restrict__ colTot){
  __shared__ int s[256];
  int t = blockIdx.x;            // bin
  int b = threadIdx.x;           // source block
  int v = (b < ABLK) ? histC[b * NBIN + t] : 0;
  s[b] = v;
  __syncthreads();
  #pragma unroll
  for (int off = 1; off < 256; off <<= 1){
    int u = (b >= off) ? s[b - off] : 0;
    __syncthreads();
    s[b] += u;
    __syncthreads();
  }
  if (b < ABLK) histE[b * NBIN + t] = s[b] - v;   // exclusive prefix within column
  if (b == ABLK - 1) colTot[t] = s[b];
}

// ---------------- scan S2: bin-level scan -> binStart ----------------
__global__ __launch_bounds__(256) void k_scanS2(const int* __restrict__ colTot, int* __restrict__ binStart){
  __shared__ int s[256];
  int t = threadIdx.x;
  int tot = (t < NBIN) ? colTot[t] : 0;
  s[t] = tot;
  __syncthreads();
  #pragma unroll
  for (int off = 1; off < 256; off <<= 1){
    int u = (t >= off) ? s[t - off] : 0;
    __syncthreads();
    s[t] += u;
    __syncthreads();
  }
  if (t < NBIN) binStart[t] = s[t] - tot;
  if (t == 0) binStart[NBIN] = NE;
}

// ---------------- k_mid: fused [bucket bin-sort (196)] + [grid-stride lin_in+conv0 GEMM (1024)] ----------------
#define B_BIN 196
#define SMSZ 20488   // bin branch: 4*NBIN*4 + 256*4 + EPB*4

__global__ __launch_bounds__(256) void k_mid(const int* __restrict__ ei,
                                             const int* __restrict__ histC, const int* __restrict__ histE,
                                             const int* __restrict__ binStart,
                                             uint32_t* __restrict__ pairs,
                                             const float* __restrict__ x,
                                             const uint16_t* __restrict__ BpIn, const float* __restrict__ b_in,
                                             const uint16_t* __restrict__ Bp0, const float* __restrict__ b0,
                                             uint16_t* __restrict__ resb, uint16_t* __restrict__ y0,
                                             uint16_t* __restrict__ z0){
  __shared__ __align__(16) char smraw[SMSZ];
  int t = threadIdx.x;
  if (blockIdx.x < B_BIN){
    // ---- bucket bin-sort: counts/offsets precomputed; 2 edge passes, zero global atomics ----
    int* loc = (int*)smraw;
    int* cur = loc + NBIN;
    int* gof = cur + NBIN;
    int* sc  = gof + NBIN + NBIN;  // keep layout within budget
    uint32_t* st = (uint32_t*)(sc + 256);
    int b = blockIdx.x;
    int cv = (t < NBIN) ? histC[b * NBIN + t] : 0;
    sc[t] = cv;
    __syncthreads();
    #pragma unroll
    for (int off = 1; off < 256; off <<= 1){
      int u = (t >= off) ? sc[t - off] : 0;
      __syncthreads();
      sc[t] += u;
      __syncthreads();
    }
    if (t < NBIN){
      int excl = sc[t] - cv;
      loc[t] = excl;
      cur[t] = excl;
      gof[t] = binStart[t] + histE[b * NBIN + t];
    }
    __syncthreads();
    int base = b * EPB;
    for (int k = t; k < EPB; k += 256){
      int e = base + k;
      if (e < NE){
        int d = ei[NE + e];
        int s0 = ei[e];
        int pos = atomicAdd(&cur[d >> 8], 1);
        st[pos] = (uint32_t)s0 | ((uint32_t)d << 16);
      }
    }
    __syncthreads();
    int cnt = min(EPB, NE - base);
    for (int k = t; k < cnt; k += 256){
      uint32_t v = st[k];
      int bin = (int)(v >> 24);
      pairs[gof[bin] + (k - loc[bin])] = v;
    }
    return;
  }
  // ---- lin_in + conv0 GEMM, grid-stride over row tiles (B-frags loaded once) ----
  uint16_t* ash = (uint16_t*)smraw;   // 16 x 128, stride 136
  int lane = t & 63, wave = t >> 6;
  short8 bIn[4][2], bC0[4][4];
  #pragma unroll
  for (int kt = 0; kt < 4; ++kt){
    #pragma unroll
    for (int n = 0; n < 2; ++n)
      bIn[kt][n] = *(const short8*)(BpIn + (size_t)((kt * 8 + wave * 2 + n) * 64 + lane) * 8);
    #pragma unroll
    for (int n = 0; n < 4; ++n)
      bC0[kt][n] = *(const short8*)(Bp0 + (size_t)((kt * 16 + wave * 4 + n) * 64 + lane) * 8);
  }
  int m = lane & 15, quad = lane >> 4;
  for (int rt = blockIdx.x - B_BIN; rt < NRT; rt += GRID_LIN){
    int r0 = rt * 16;
    const float* xrow = x + (size_t)(r0 + m) * 128 + quad * 8;
    short8 af[4];
    #pragma unroll
    for (int kt = 0; kt < 4; ++kt){
      float4 p = *(const float4*)(xrow + kt * 32);
      float4 q2 = *(const float4*)(xrow + kt * 32 + 4);
      short8 a;
      a[0] = (short)f2bf(p.x);  a[1] = (short)f2bf(p.y);
      a[2] = (short)f2bf(p.z);  a[3] = (short)f2bf(p.w);
      a[4] = (short)f2bf(q2.x); a[5] = (short)f2bf(q2.y);
      a[6] = (short)f2bf(q2.z); a[7] = (short)f2bf(q2.w);
      af[kt] = a;
    }
    floatx4 accH[2];
    #pragma unroll
    for (int n = 0; n < 2; ++n) accH[n] = (floatx4){0.f, 0.f, 0.f, 0.f};
    #pragma unroll
    for (int kt = 0; kt < 4; ++kt)
      #pragma unroll
      for (int n = 0; n < 2; ++n)
        accH[n] = __builtin_amdgcn_mfma_f32_16x16x32_bf16(af[kt], bIn[kt][n], accH[n], 0, 0, 0);
    int rbase = r0 + quad * 4;
    __syncthreads();   // protect ash from previous iteration's readers
    #pragma unroll
    for (int n = 0; n < 2; ++n){
      int c = (wave * 2 + n) * 16 + m;
      float bi = b_in[c];
      #pragma unroll
      for (int i = 0; i < 4; ++i){
        float hh = accH[n][i] + bi;
        int row = rbase + i;
        resb[(size_t)row * 128 + c] = f2bf(0.2f * hh);
        ash[(quad * 4 + i) * 136 + c] = f2bf(fmaxf(hh, 0.f));
      }
    }
    __syncthreads();
    short8 af2[4];
    #pragma unroll
    for (int kt = 0; kt < 4; ++kt)
      af2[kt] = *(const short8*)&ash[m * 136 + quad * 8 + kt * 32];
    floatx4 acc[4];
    #pragma unroll
    for (int n = 0; n < 4; ++n) acc[n] = (floatx4){0.f, 0.f, 0.f, 0.f};
    #pragma unroll
    for (int kt = 0; kt < 4; ++kt)
      #pragma unroll
      for (int n = 0; n < 4; ++n)
        acc[n] = __builtin_amdgcn_mfma_f32_16x16x32_bf16(af2[kt], bC0[kt][n], acc[n], 0, 0, 0);
    #pragma unroll
    for (int n = 0; n < 4; ++n){
      int c = (wave * 4 + n) * 16 + m;
      #pragma unroll
      for (int i = 0; i < 4; ++i){
        float v = acc[n][i];
        int row = rbase + i;
        if (c < 128) y0[(size_t)row * 128 + c] = f2bf(v);
        else         z0[(size_t)row * 128 + (c - 128)] = f2bf(v + b0[c - 128]);
      }
    }
  }
}

// ---------------- pass B: per-bucket counting sort -> rowp + colx(u16) ----------------
__global__ __launch_bounds__(256) void k_csr(const uint32_t* __restrict__ pairs, const int* __restrict__ binStart,
                                             int* __restrict__ rowp, uint16_t* __restrict__ colx){
  __shared__ uint32_t pl[BCAP];
  __shared__ uint16_t stg[BCAP];
  __shared__ int h[256], sc[256];
  int i = blockIdx.x, t = threadIdx.x;
  int p0 = binStart[i], p1 = binStart[i + 1];
  int cnt = min(p1 - p0, BCAP);
  for (int k = t; k < cnt; k += 256) pl[k] = pairs[p0 + k];
  h[t] = 0;
  __syncthreads();
  for (int k = t; k < cnt; k += 256) atomicAdd(&h[(pl[k] >> 16) & 255], 1);
  __syncthreads();
  int cv = h[t];
  sc[t] = cv;
  __syncthreads();
  #pragma unroll
  for (int off = 1; off < 256; off <<= 1){
    int u = (t >= off) ? sc[t - off] : 0;
    __syncthreads();
    sc[t] += u;
    __syncthreads();
  }
  int excl = sc[t] - cv;
  int n0 = i << 8;
  int nc = min(256, NN - n0);
  if (t < nc) rowp[n0 + t] = p0 + excl;
  if (i == NBIN - 1 && t == 0) rowp[NN] = NE;
  h[t] = excl;   // becomes cursor
  __syncthreads();
  for (int k = t; k < cnt; k += 256){
    uint32_t v = pl[k];
    int pos = atomicAdd(&h[(v >> 16) & 255], 1);
    stg[pos] = (uint16_t)(v & 0xFFFFu);
  }
  __syncthreads();
  for (int k = t; k < cnt; k += 256) colx[p0 + k] = stg[k];
}

// ------------- GEMM: A[N,128]bf16 @ Bp[128, NCOL] -> epilogue -------------
template<int NTW, int MODE>
__global__ __launch_bounds__(256) void k_gemm(const uint16_t* __restrict__ A, const uint16_t* __restrict__ Bp,
                                              const float* __restrict__ bias,
                                              uint16_t* __restrict__ o0, uint16_t* __restrict__ o1,
                                              float* __restrict__ o2){
  const int NTT = 4 * NTW;
  int lane = threadIdx.x & 63;
  int wave = threadIdx.x >> 6;
  short8 bfrag[4][NTW];
  #pragma unroll
  for (int kt = 0; kt < 4; ++kt)
    #pragma unroll
    for (int n = 0; n < NTW; ++n)
      bfrag[kt][n] = *(const short8*)(Bp + (size_t)((kt * NTT + wave * NTW + n) * 64 + lane) * 8);

  int m = lane & 15, quad = lane >> 4;
  const int nrt = NN / 16;
  for (int rt = blockIdx.x; rt < nrt; rt += gridDim.x){
    int r0 = rt * 16;
    const uint16_t* arow = A + (size_t)(r0 + m) * 128 + quad * 8;
    short8 af[4];
    #pragma unroll
    for (int kt = 0; kt < 4; ++kt) af[kt] = *(const short8*)(arow + kt * 32);
    floatx4 acc[NTW];
    #pragma unroll
    for (int n = 0; n < NTW; ++n) acc[n] = (floatx4){0.f, 0.f, 0.f, 0.f};
    #pragma unroll
    for (int kt = 0; kt < 4; ++kt)
      #pragma unroll
      for (int n = 0; n < NTW; ++n)
        acc[n] = __builtin_amdgcn_mfma_f32_16x16x32_bf16(af[kt], bfrag[kt][n], acc[n], 0, 0, 0);

    int rbase = r0 + quad * 4;
    #pragma unroll
    for (int n = 0; n < NTW; ++n){
      int c = (wave * NTW + n) * 16 + m;
      #pragma unroll
      for (int i = 0; i < 4; ++i){
        float v = acc[n][i];
        int row = rbase + i;
        if (MODE == 1){
          if (c < 128) o0[(size_t)row * 128 + c] = f2bf(v);
          else         o1[(size_t)row * 128 + (c - 128)] = f2bf(v + bias[c - 128]);
        } else {
          if (c < 64) o0[(size_t)row * 64 + c] = f2bf(v);
          else        o2[(size_t)row * 64 + (c - 64)] = v + bias[c - 64];
        }
      }
    }
  }
}

// ------------- aggregation: one wave per node; quarter-wave (16 lanes x uint4) per edge -------------
__global__ __launch_bounds__(256) void agg_mid(const uint4* __restrict__ yb, const uint4* __restrict__ zb,
                                               const uint4* __restrict__ resb,
                                               const uint16_t* __restrict__ colx, const int* __restrict__ rowp,
                                               uint4* __restrict__ hb_out){
  int wid = blockIdx.x * 4 + (threadIdx.x >> 6);
  if (wid >= NN) return;
  int lane = threadIdx.x & 63;
  int q = lane >> 4, sub = lane & 15;
  int e0 = rowp[wid], e1 = rowp[wid + 1];
  float a0 = 0.f, a1 = 0.f, a2 = 0.f, a3 = 0.f, a4 = 0.f, a5 = 0.f, a6 = 0.f, a7 = 0.f;
  int e = e0 + q;
  for (; e + 12 < e1; e += 16){
    uint4 v0 = yb[(size_t)colx[e]      * 16 + sub];
    uint4 v1 = yb[(size_t)colx[e + 4]  * 16 + sub];
    uint4 v2 = yb[(size_t)colx[e + 8]  * 16 + sub];
    uint4 v3 = yb[(size_t)colx[e + 12] * 16 + sub];
    a0 += bflo(v0.x) + bflo(v1.x) + bflo(v2.x) + bflo(v3.x);
    a1 += bfhi(v0.x) + bfhi(v1.x) + bfhi(v2.x) + bfhi(v3.x);
    a2 += bflo(v0.y) + bflo(v1.y) + bflo(v2.y) + bflo(v3.y);
    a3 += bfhi(v0.y) + bfhi(v1.y) + bfhi(v2.y) + bfhi(v3.y);
    a4 += bflo(v0.z) + bflo(v1.z) + bflo(v2.z) + bflo(v3.z);
    a5 += bfhi(v0.z) + bfhi(v1.z) + bfhi(v2.z) + bfhi(v3.z);
    a6 += bflo(v0.w) + bflo(v1.w) + bflo(v2.w) + bflo(v3.w);
    a7 += bfhi(v0.w) + bfhi(v1.w) + bfhi(v2.w) + bfhi(v3.w);
  }
  for (; e < e1; e += 4){
    uint4 v = yb[(size_t)colx[e] * 16 + sub];
    a0 += bflo(v.x); a1 += bfhi(v.x); a2 += bflo(v.y); a3 += bfhi(v.y);
    a4 += bflo(v.z); a5 += bfhi(v.z); a6 += bflo(v.w); a7 += bfhi(v.w);
  }
  #pragma unroll
  for (int off = 16; off < 64; off <<= 1){
    a0 += __shfl_xor(a0, off, 64);
    a1 += __shfl_xor(a1, off, 64);
    a2 += __shfl_xor(a2, off, 64);
    a3 += __shfl_xor(a3, off, 64);
    a4 += __shfl_xor(a4, off, 64);
    a5 += __shfl_xor(a5, off, 64);
    a6 += __shfl_xor(a6, off, 64);
    a7 += __shfl_xor(a7, off, 64);
  }
  int deg = e1 - e0;
  float inv = deg > 0 ? 1.f / (float)deg : 0.f;
  if (q == 0){
    uint4 zv = zb[(size_t)wid * 16 + sub];
    uint4 rv = resb[(size_t)wid * 16 + sub];
    float w0 = fmaxf(a0 * inv + bflo(zv.x), 0.f) + bflo(rv.x);
    float w1 = fmaxf(a1 * inv + bfhi(zv.x), 0.f) + bfhi(rv.x);
    float w2 = fmaxf(a2 * inv + bflo(zv.y), 0.f) + bflo(rv.y);
    float w3 = fmaxf(a3 * inv + bfhi(zv.y), 0.f) + bfhi(rv.y);
    float w4 = fmaxf(a4 * inv + bflo(zv.z), 0.f) + bflo(rv.z);
    float w5 = fmaxf(a5 * inv + bfhi(zv.z), 0.f) + bfhi(rv.z);
    float w6 = fmaxf(a6 * inv + bflo(zv.w), 0.f) + bflo(rv.w);
    float w7 = fmaxf(a7 * inv + bfhi(zv.w), 0.f) + bfhi(rv.w);
    uint4 o;
    o.x = (uint32_t)f2bf(w0) | ((uint32_t)f2bf(w1) << 16);
    o.y = (uint32_t)f2bf(w2) | ((uint32_t)f2bf(w3) << 16);
    o.z = (uint32_t)f2bf(w4) | ((uint32_t)f2bf(w5) << 16);
    o.w = (uint32_t)f2bf(w6) | ((uint32_t)f2bf(w7) << 16);
    hb_out[(size_t)wid * 16 + sub] = o;
  }
}

// ------------- final aggregation + log_softmax (quarter-wave, uint2 loads, 4 dims/lane) -------------
__global__ __launch_bounds__(256) void agg_out(const uint2* __restrict__ yb2, const float* __restrict__ z2,
                                               const uint16_t* __restrict__ colx, const int* __restrict__ rowp,
                                               float* __restrict__ out){
  int wid = blockIdx.x * 4 + (threadIdx.x >> 6);
  if (wid >= NN) return;
  int lane = threadIdx.x & 63;
  int q = lane >> 4, sub = lane & 15;
  int e0 = rowp[wid], e1 = rowp[wid + 1];
  float a0 = 0.f, a1 = 0.f, a2 = 0.f, a3 = 0.f;
  int e = e0 + q;
  for (; e + 12 < e1; e += 16){
    uint2 v0 = yb2[(size_t)colx[e]      * 16 + sub];
    uint2 v1 = yb2[(size_t)colx[e + 4]  * 16 + sub];
    uint2 v2 = yb2[(size_t)colx[e + 8]  * 16 + sub];
    uint2 v3 = yb2[(size_t)colx[e + 12] * 16 + sub];
    a0 += bflo(v0.x) + bflo(v1.x) + bflo(v2.x) + bflo(v3.x);
    a1 += bfhi(v0.x) + bfhi(v1.x) + bfhi(v2.x) + bfhi(v3.x);
    a2 += bflo(v0.y) + bflo(v1.y) + bflo(v2.y) + bflo(v3.y);
    a3 += bfhi(v0.y) + bfhi(v1.y) + bfhi(v2.y) + bfhi(v3.y);
  }
  for (; e < e1; e += 4){
    uint2 v = yb2[(size_t)colx[e] * 16 + sub];
    a0 += bflo(v.x); a1 += bfhi(v.x); a2 += bflo(v.y); a3 += bfhi(v.y);
  }
  #pragma unroll
  for (int off = 16; off < 64; off <<= 1){
    a0 += __shfl_xor(a0, off, 64);
    a1 += __shfl_xor(a1, off, 64);
    a2 += __shfl_xor(a2, off, 64);
    a3 += __shfl_xor(a3, off, 64);
  }
  int deg = e1 - e0;
  float inv = deg > 0 ? 1.f / (float)deg : 0.f;
  float4 zv = ((const float4*)z2)[(size_t)wid * 16 + sub];
  float v0 = a0 * inv + zv.x;
  float v1 = a1 * inv + zv.y;
  float v2 = a2 * inv + zv.z;
  float v3 = a3 * inv + zv.w;
  float mx = fmaxf(fmaxf(v0, v1), fmaxf(v2, v3));
  #pragma unroll
  for (int off = 1; off < 16; off <<= 1) mx = fmaxf(mx, __shfl_xor(mx, off, 64));
  float sm = __expf(v0 - mx) + __expf(v1 - mx) + __expf(v2 - mx) + __expf(v3 - mx);
  #pragma unroll
  for (int off = 1; off < 16; off <<= 1) sm += __shfl_xor(sm, off, 64);
  if (q == 0){
    float ls = __logf(sm);
    float4 o = make_float4((v0 - mx) - ls, (v1 - mx) - ls, (v2 - mx) - ls, (v3 - mx) - ls);
    ((float4*)out)[(size_t)wid * 16 + sub] = o;
  }
}

extern "C" void kernel_launch(void* const* d_in, const int* in_sizes, int n_in,
                              void* d_out, int out_size, void* d_ws, size_t ws_size,
                              hipStream_t stream){
  const float* x    = (const float*)d_in[0];
  const int*   ei   = (const int*)d_in[1];
  const float* w_in = (const float*)d_in[2];
  const float* b_in = (const float*)d_in[3];
  const float* w_l0 = (const float*)d_in[4];
  const float* w_r0 = (const float*)d_in[5];
  const float* b0   = (const float*)d_in[6];
  const float* w_l1 = (const float*)d_in[7];
  const float* w_r1 = (const float*)d_in[8];
  const float* b1   = (const float*)d_in[9];
  const float* w_l2 = (const float*)d_in[10];
  const float* w_r2 = (const float*)d_in[11];
  const float* b2   = (const float*)d_in[12];
  float* out = (float*)d_out;

  char* ws = (char*)d_ws;
  size_t off = 0;
  auto take = [&](size_t bytes) -> char* {
    char* p = ws + off;
    off = (off + bytes + 1023) & ~(size_t)1023;
    return p;
  };
  uint16_t* hb   = (uint16_t*)take((size_t)NN * 128 * 2);   // agg outputs
  uint16_t* resb = (uint16_t*)take((size_t)NN * 128 * 2);   // 0.2*inp
  uint16_t* y0   = (uint16_t*)take((size_t)NN * 128 * 2);   // y (reused each conv)
  uint16_t* z0   = (uint16_t*)take((size_t)NN * 128 * 2);   // z (reused; fp32 z2 at end)
  uint32_t* pairs = (uint32_t*)take((size_t)NE * 4);
  uint16_t* colx  = (uint16_t*)take((size_t)NE * 2);
  int* histC    = (int*)take((size_t)NBIN * ABLK * 4);
  int* histE    = (int*)take((size_t)NBIN * ABLK * 4);
  int* colTot   = (int*)take((size_t)NBIN * 4);
  int* binStart = (int*)take((size_t)(NBIN + 1) * 4);
  int* rowp     = (int*)take((size_t)(NN + 1) * 4);
  uint16_t* BpIn = (uint16_t*)take(128 * 128 * 2);
  uint16_t* Bp0  = (uint16_t*)take(128 * 256 * 2);
  uint16_t* Bp1  = (uint16_t*)take(128 * 256 * 2);
  uint16_t* Bp2  = (uint16_t*)take(128 * 128 * 2);
  uint16_t* y2 = y0;
  float*    z2 = (float*)z0;
  (void)ws_size; (void)in_sizes; (void)n_in; (void)out_size;

  // prep: bucket histogram (counts kept in histC) + weight packs
  k_prep<<<B_HIST + B_PIN + B_P0 + B_P1 + B_P2, 256, 0, stream>>>(
      ei, histC, w_in, w_l0, w_r0, w_l1, w_r1, w_l2, w_r2, BpIn, Bp0, Bp1, Bp2);

  // parallel offset computation (histC preserved; exclusive prefixes in histE)
  k_scanS1<<<NBIN, 256, 0, stream>>>(histC, histE, colTot);
  k_scanS2<<<1, 256, 0, stream>>>(colTot, binStart);

  // fused: bucket bin-sort (196 blocks, 2 edge passes) + grid-stride lin_in+conv0 GEMM (1024 blocks)
  k_mid<<<B_BIN + GRID_LIN, 256, 0, stream>>>(ei, histC, histE, binStart, pairs, x,
                                              BpIn, b_in, Bp0, b0, resb, y0, z0);

  // per-bucket counting sort -> rowp + colx
  k_csr<<<NBIN, 256, 0, stream>>>(pairs, binStart, rowp, colx);

  // conv0 agg: y0,z0,res -> hb
  agg_mid<<<NN / 4, 256, 0, stream>>>((const uint4*)y0, (const uint4*)z0, (const uint4*)resb,
                                      colx, rowp, (uint4*)hb);
  // conv1 gemm: hb -> y0, z0
  k_gemm<4, 1><<<1024, 256, 0, stream>>>(hb, Bp1, b1, y0, z0, nullptr);

  // conv1 agg: y0,z0,res -> hb
  agg_mid<<<NN / 4, 256, 0, stream>>>((const uint4*)y0, (const uint4*)z0, (const uint4*)resb,
                                      colx, rowp, (uint4*)hb);
  // conv2 gemm: hb -> y2(bf16 64c), z2(fp32 64c)
  k_gemm<2, 2><<<1024, 256, 0, stream>>>(hb, Bp2, b2, y2, nullptr, z2);

  // conv2 agg + log_softmax
  agg_out<<<NN / 4, 256, 0, stream>>>((const uint2*)y2, z2, colx, rowp, out);
}